// Round 12
// baseline (1510.103 us; speedup 1.0000x reference)
//
#include <hip/hip_runtime.h>

typedef __attribute__((ext_vector_type(8))) short bfrag;   // 8 bf16 (4 VGPRs)
typedef __attribute__((ext_vector_type(4))) float f32x4;   // MFMA C/D
typedef __attribute__((ext_vector_type(4))) int i32x4;     // 16B moves

#define NT 512      // seq len
#define NB 64       // batch
#define KD 512      // D == H == 512
#define NG 2048     // 4*H gate rows
#define GB 4        // batch blocks (16 batch each)
#define GH 16       // h-slices (32 dims each)
#define NWREC 64    // recurrence WGs
#define NWGF 256    // fused grid
#define NWORK (NWGF - NWREC)
#define NJOBS (32 * NT)   // xproj tiles: 32 n-blocks x 512 t

#define YS_SZ (NT * NB * KD)
#define HT_OFF YS_SZ
#define CT_OFF (YS_SZ + NB * KD)

// mailbox: [2 parity][GB blocks][256 pairs][16 batch] of u64 {tag32 | bf16x2}
#define MB_BLK_WORDS 4096
#define MB_PAR_WORDS (GB * MB_BLK_WORDS)
#define MB_BYTES (2 * MB_PAR_WORDS * 8)   // 262144

__device__ __forceinline__ unsigned short f2bf(float f) {
  unsigned u = __float_as_uint(f);
  u += 0x7fffu + ((u >> 16) & 1u);
  return (unsigned short)(u >> 16);
}
__device__ __forceinline__ float bf2f(unsigned short h) {
  return __uint_as_float(((unsigned)h) << 16);
}
__device__ __forceinline__ float sigm(float v) { return 1.f / (1.f + __expf(-v)); }
__device__ __forceinline__ float tanh_f(float v) { return 1.f - 2.f / (__expf(2.f * v) + 1.f); }

// ---------------- fp32 -> bf16 convert (Wih only) ----------------
__global__ __launch_bounds__(256) void cvt_bf16(const float* __restrict__ src,
                                                unsigned short* __restrict__ dst, int n8) {
  int i = blockIdx.x * 256 + threadIdx.x;
  if (i >= n8) return;
  const float4 a = *(const float4*)(src + (size_t)i * 8);
  const float4 b = *(const float4*)(src + (size_t)i * 8 + 4);
  i32x4 v;
  v.x = (int)(f2bf(a.x) | ((unsigned)f2bf(a.y) << 16));
  v.y = (int)(f2bf(a.z) | ((unsigned)f2bf(a.w) << 16));
  v.z = (int)(f2bf(b.x) | ((unsigned)f2bf(b.y) << 16));
  v.w = (int)(f2bf(b.z) | ((unsigned)f2bf(b.w) << 16));
  *(i32x4*)(dst + (size_t)i * 8) = v;
}

// ---------------- Fused kernel: recurrence (WG 0..63) + xproj workers (WG 64..255) ------
// Workers: grind (n0,t) tiles t-ascending; x_proj stored with sc1 (agent) stores; after a
// full drain (__syncthreads) lane0 bumps xcnt[t] (R2-proven release idiom). Recurrence:
// R6/R11 loop verbatim, plus a one-step-lookahead watermark on xcnt so xp loads are
// provably ordered after producer completion with zero steady-state latency.
template <int XP32>
__global__ __launch_bounds__(256, 1) void lstm_fused(const float* __restrict__ Whh,
                                                     const unsigned short* __restrict__ WihB,
                                                     const float* __restrict__ x,
                                                     void* __restrict__ XPv,
                                                     const float* __restrict__ bih,
                                                     const float* __restrict__ bhh,
                                                     const float* __restrict__ h0,
                                                     const float* __restrict__ c0,
                                                     unsigned long long* __restrict__ mbox,
                                                     unsigned int* __restrict__ xcnt,
                                                     float* __restrict__ out) {
  __shared__ unsigned short hl[16 * 512];  // rec: h block, XOR-swizzled (16KB)
  __shared__ float hf[16 * 33];            // rec: h_new transpose tile
  __shared__ unsigned short Wt[64 * 40];   // worker: W tile
  __shared__ unsigned short Xt[64 * 40];   // worker: X tile

  const int tid = threadIdx.x;
  const int lane = tid & 63, wid = tid >> 6;
  const int g = lane >> 4, cc = lane & 15;

  if (blockIdx.x >= NWREC) {
    // ================= worker role: xproj tiles =================
    const int srow = tid >> 2, schunk = (tid & 3) * 8;
    for (int jj = (int)blockIdx.x - NWREC; jj < NJOBS; jj += NWORK) {
      const int t = jj >> 5, n0 = (jj & 31) << 6;
      f32x4 acc[4] = {};
      for (int kb = 0; kb < KD; kb += 32) {
        __syncthreads();
        *(i32x4*)&Wt[srow * 40 + schunk] =
            *(const i32x4*)(WihB + (size_t)(n0 + srow) * KD + kb + schunk);
        {
          const float* xs = x + ((size_t)t * 64 + srow) * KD + kb + schunk;
          const float4 a = *(const float4*)xs;
          const float4 b = *(const float4*)(xs + 4);
          i32x4 v;
          v.x = (int)(f2bf(a.x) | ((unsigned)f2bf(a.y) << 16));
          v.y = (int)(f2bf(a.z) | ((unsigned)f2bf(a.w) << 16));
          v.z = (int)(f2bf(b.x) | ((unsigned)f2bf(b.y) << 16));
          v.w = (int)(f2bf(b.z) | ((unsigned)f2bf(b.w) << 16));
          *(i32x4*)&Xt[srow * 40 + schunk] = v;
        }
        __syncthreads();
        bfrag af = *(const bfrag*)&Wt[(wid * 16 + cc) * 40 + g * 8];
#pragma unroll
        for (int mt = 0; mt < 4; ++mt) {
          bfrag bf = *(const bfrag*)&Xt[(mt * 16 + cc) * 40 + g * 8];
          acc[mt] = __builtin_amdgcn_mfma_f32_16x16x32_bf16(af, bf, acc[mt], 0, 0, 0);
        }
      }
      const int nl = wid * 16 + g * 4;
      float bi[4];
#pragma unroll
      for (int r = 0; r < 4; ++r) bi[r] = bih[n0 + nl + r];
#pragma unroll
      for (int mt = 0; mt < 4; ++mt) {
#pragma unroll
        for (int r = 0; r < 4; ++r) {
          float v = acc[mt][r] + bi[r];
          size_t idx = ((size_t)t * NG + n0 + nl + r) * 64 + mt * 16 + cc;
          if constexpr (XP32)
            __hip_atomic_store((unsigned*)XPv + idx, __float_as_uint(v), __ATOMIC_RELAXED,
                               __HIP_MEMORY_SCOPE_AGENT);
          else
            __hip_atomic_store((unsigned short*)XPv + idx, f2bf(v), __ATOMIC_RELAXED,
                               __HIP_MEMORY_SCOPE_AGENT);
        }
      }
      __syncthreads();  // drains all waves' stores before the release-add
      if (tid == 0)
        __hip_atomic_fetch_add(xcnt + t, 1u, __ATOMIC_RELAXED, __HIP_MEMORY_SCOPE_AGENT);
    }
    return;
  }

  // ================= recurrence role (R6/R11 structure) =================
  const int blk = blockIdx.x >> 4, slice = blockIdx.x & 15;
  const int b0 = blk * 16, d0 = slice * 32;

  // ---- publish our slice of h0 (tag=1) into parity-0 mailbox, ASAP (1 word/thread)
  {
    const int lp = tid >> 4, b = tid & 15;
    const int d = d0 + lp * 2;
    const float* hp = h0 + (size_t)(b0 + b) * KD + d;
    unsigned d32 = (unsigned)f2bf(hp[0]) | ((unsigned)f2bf(hp[1]) << 16);
    __hip_atomic_store(mbox + (size_t)blk * MB_BLK_WORDS + ((d0 >> 1) + lp) * 16 + b,
                       (1ull << 32) | (unsigned long long)d32, __ATOMIC_RELAXED,
                       __HIP_MEMORY_SCOPE_AGENT);
  }

  // ---- preload W_hh slice into registers with inline fp32->bf16 convert
  bfrag w[2][16];
#pragma unroll
  for (int j = 0; j < 2; ++j) {
    const int tt = wid * 2 + j;
    const int r = tt * 16 + cc;  // A-operand row = lane&15
    const size_t n = (size_t)(r & 3) * KD + d0 + (r >> 2);
#pragma unroll
    for (int ks = 0; ks < 16; ++ks) {
      const float* wp = Whh + n * KD + ks * 32 + g * 8;
      const float4 a = *(const float4*)wp;
      const float4 b = *(const float4*)(wp + 4);
      bfrag fr;
      fr[0] = (short)f2bf(a.x); fr[1] = (short)f2bf(a.y);
      fr[2] = (short)f2bf(a.z); fr[3] = (short)f2bf(a.w);
      fr[4] = (short)f2bf(b.x); fr[5] = (short)f2bf(b.y);
      fr[6] = (short)f2bf(b.z); fr[7] = (short)f2bf(b.w);
      w[j][ks] = fr;
    }
  }
  float bh[2][4], creg[2];
#pragma unroll
  for (int j = 0; j < 2; ++j) {
    const int d = d0 + (wid * 2 + j) * 4 + g;
#pragma unroll
    for (int r = 0; r < 4; ++r) bh[j][r] = bhh[r * KD + d];
    creg[j] = c0[(b0 + cc) * KD + d];
  }

  bool cnt_ok = false;  // xcnt[t] >= 32 confirmed last step?

  for (int t = 0; t < NT; ++t) {
    // ---- xp watermark gate (spin only when workers are behind: startup)
    if (!cnt_ok) {
      const unsigned int* cp = xcnt + t;
      for (;;) {
        unsigned c;
        asm volatile("global_load_dword %0, %1, off sc1\n\ts_waitcnt vmcnt(0)"
                     : "=&v"(c) : "v"(cp) : "memory");
        if (__all(c >= 32u)) break;
      }
    }
    // ---- xp loads (sc1: data lives at the coherence point)
    float xp[2][4];
#pragma unroll
    for (int j = 0; j < 2; ++j) {
      const int d = d0 + (wid * 2 + j) * 4 + g;
#pragma unroll
      for (int r = 0; r < 4; ++r) {
        size_t idx = ((size_t)t * NG + r * KD + d) * 64 + b0 + cc;
        if constexpr (XP32) {
          unsigned uv = __hip_atomic_load((const unsigned*)XPv + idx, __ATOMIC_RELAXED,
                                          __HIP_MEMORY_SCOPE_AGENT);
          xp[j][r] = __uint_as_float(uv);
        } else {
          unsigned short sv = __hip_atomic_load((const unsigned short*)XPv + idx,
                                                __ATOMIC_RELAXED, __HIP_MEMORY_SCOPE_AGENT);
          xp[j][r] = bf2f(sv);
        }
      }
    }
    // ---- single-hop receive: batched asm poll of 16 tagged words (+ xcnt[t+1] lookahead)
    const unsigned long long* mbr =
        mbox + (size_t)(t & 1) * MB_PAR_WORDS + (size_t)blk * MB_BLK_WORDS;
    const unsigned int* cpn = xcnt + t + 1;
    const unsigned tg = (unsigned)(t + 1);
    unsigned cn;
    unsigned long long q0, q1, q2, q3, q4, q5, q6, q7, q8, q9, q10, q11, q12, q13, q14, q15;
#define PISSUE(r)                                                        \
  asm volatile("global_load_dwordx2 %0, %1, %2 sc1"                      \
               : "=v"(q##r)                                              \
               : "v"((unsigned)(tid * 8 + r * 2048)), "s"(mbr));
    for (;;) {
      PISSUE(0) PISSUE(1) PISSUE(2) PISSUE(3) PISSUE(4) PISSUE(5) PISSUE(6) PISSUE(7)
      PISSUE(8) PISSUE(9) PISSUE(10) PISSUE(11) PISSUE(12) PISSUE(13) PISSUE(14) PISSUE(15)
      asm volatile("global_load_dword %0, %1, off sc1" : "=v"(cn) : "v"(cpn));
      asm volatile("s_waitcnt vmcnt(0)" ::: "memory");
      __builtin_amdgcn_sched_barrier(0);
      unsigned ok = 1u;
#define PCHK(r) ok &= ((unsigned)(q##r >> 32) == tg) ? 1u : 0u;
      PCHK(0) PCHK(1) PCHK(2) PCHK(3) PCHK(4) PCHK(5) PCHK(6) PCHK(7)
      PCHK(8) PCHK(9) PCHK(10) PCHK(11) PCHK(12) PCHK(13) PCHK(14) PCHK(15)
      if (__all(ok)) break;
    }
#undef PISSUE
#undef PCHK
    cnt_ok = __all(cn >= 32u);
    // unpack into swizzled LDS: word (r*256+tid) = pair p = r*16 + (tid>>4), batch b = tid&15
    {
      const int b = tid & 15, pq = tid >> 4;
      const int bb = b * 1024, bx = (b & 7) << 4;
#define PUNP(r) \
  *(unsigned*)((char*)hl + bb + (((r * 16 + pq) * 4) ^ bx)) = (unsigned)q##r;
      PUNP(0) PUNP(1) PUNP(2) PUNP(3) PUNP(4) PUNP(5) PUNP(6) PUNP(7)
      PUNP(8) PUNP(9) PUNP(10) PUNP(11) PUNP(12) PUNP(13) PUNP(14) PUNP(15)
#undef PUNP
    }
    __syncthreads();
    // gates = W_slice @ h^T  (4 accumulators: chains of 8)
    f32x4 p00 = {0.f, 0.f, 0.f, 0.f}, p01 = {0.f, 0.f, 0.f, 0.f};
    f32x4 p10 = {0.f, 0.f, 0.f, 0.f}, p11 = {0.f, 0.f, 0.f, 0.f};
#pragma unroll
    for (int ks = 0; ks < 8; ++ks) {
      const int off = ks * 64 + g * 16;
      bfrag hb = *(const bfrag*)((const char*)hl + cc * 1024 + (off ^ ((cc & 7) << 4)));
      p00 = __builtin_amdgcn_mfma_f32_16x16x32_bf16(w[0][ks], hb, p00, 0, 0, 0);
      p10 = __builtin_amdgcn_mfma_f32_16x16x32_bf16(w[1][ks], hb, p10, 0, 0, 0);
    }
#pragma unroll
    for (int ks = 8; ks < 16; ++ks) {
      const int off = ks * 64 + g * 16;
      bfrag hb = *(const bfrag*)((const char*)hl + cc * 1024 + (off ^ ((cc & 7) << 4)));
      p01 = __builtin_amdgcn_mfma_f32_16x16x32_bf16(w[0][ks], hb, p01, 0, 0, 0);
      p11 = __builtin_amdgcn_mfma_f32_16x16x32_bf16(w[1][ks], hb, p11, 0, 0, 0);
    }
    const f32x4 acc0 = p00 + p01, acc1 = p10 + p11;
    // pointwise (i,f,g,o thread-local)
    float hnv[2];
#pragma unroll
    for (int j = 0; j < 2; ++j) {
      const f32x4 a = j ? acc1 : acc0;
      float gi = a[0] + xp[j][0] + bh[j][0];
      float gf = a[1] + xp[j][1] + bh[j][1];
      float gg = a[2] + xp[j][2] + bh[j][2];
      float go = a[3] + xp[j][3] + bh[j][3];
      float cn2 = sigm(gf) * creg[j] + sigm(gi) * tanh_f(gg);
      creg[j] = cn2;
      hnv[j] = sigm(go) * tanh_f(cn2);
      if (t == NT - 1) out[CT_OFF + (size_t)(b0 + cc) * KD + d0 + (wid * 8 + j * 4 + g)] = cn2;
    }
    // ---- single-hop publish: pair dims via shfl, store (tag|bf16x2) words NOW; no drain
    {
      unsigned long long* mbw =
          mbox + (size_t)((t + 1) & 1) * MB_PAR_WORDS + (size_t)blk * MB_BLK_WORDS;
      const unsigned long long tagn = (unsigned long long)(unsigned)(t + 2) << 32;
      const float o0 = __shfl_xor(hnv[0], 16);
      const float o1 = __shfl_xor(hnv[1], 16);
      if (!(g & 1)) {
        const unsigned w0 = (unsigned)f2bf(hnv[0]) | ((unsigned)f2bf(o0) << 16);
        const unsigned w1 = (unsigned)f2bf(hnv[1]) | ((unsigned)f2bf(o1) << 16);
        const int p0 = (d0 >> 1) + wid * 4 + (g >> 1);
        const int p1 = p0 + 2;
        __hip_atomic_store(mbw + p0 * 16 + cc, tagn | (unsigned long long)w0,
                           __ATOMIC_RELAXED, __HIP_MEMORY_SCOPE_AGENT);
        __hip_atomic_store(mbw + p1 * 16 + cc, tagn | (unsigned long long)w1,
                           __ATOMIC_RELAXED, __HIP_MEMORY_SCOPE_AGENT);
      }
    }
    // transpose h_new for coalesced fp32 output stores (off critical path)
#pragma unroll
    for (int j = 0; j < 2; ++j) hf[cc * 33 + (wid * 8 + j * 4 + g)] = hnv[j];
    __syncthreads();
    if (tid < 128) {
      const int b = tid >> 3, dg = (tid & 7) * 4;
      float4 hv;
      hv.x = hf[b * 33 + dg];
      hv.y = hf[b * 33 + dg + 1];
      hv.z = hf[b * 33 + dg + 2];
      hv.w = hf[b * 33 + dg + 3];
      *(float4*)(out + (size_t)t * NB * KD + (size_t)(b0 + b) * KD + d0 + dg) = hv;
      if (t == NT - 1)
        *(float4*)(out + HT_OFF + (size_t)(b0 + b) * KD + d0 + dg) = hv;
    }
  }
}

extern "C" void kernel_launch(void* const* d_in, const int* in_sizes, int n_in,
                              void* d_out, int out_size, void* d_ws, size_t ws_size,
                              hipStream_t stream) {
  const float* x = (const float*)d_in[0];
  const float* h0 = (const float*)d_in[1];
  const float* c0 = (const float*)d_in[2];
  const float* Wih = (const float*)d_in[3];
  const float* Whh = (const float*)d_in[4];
  const float* bih = (const float*)d_in[5];
  const float* bhh = (const float*)d_in[6];
  float* out = (float*)d_out;
  char* ws = (char*)d_ws;

  unsigned long long* mbox = (unsigned long long*)ws;                 // 256KB
  unsigned int* xcnt = (unsigned int*)(ws + MB_BYTES);                // 4KB (1024 u32)
  unsigned short* WihB = (unsigned short*)(ws + MB_BYTES + 4096);     // 2MB
  const size_t xp_off = MB_BYTES + 4096 + 2097152;
  void* XP = (void*)(ws + xp_off);
  const bool xp32 = ws_size >= xp_off + (size_t)NT * NG * 64 * 4;

  hipMemsetAsync(ws, 0, MB_BYTES + 4096, stream);  // mailbox tags + xcnt (replay-safe)

  const int nw8 = NG * KD / 8;  // Wih convert only
  cvt_bf16<<<dim3(nw8 / 256), 256, 0, stream>>>(Wih, WihB, nw8);

  if (xp32) {
    lstm_fused<1><<<dim3(NWGF), 256, 0, stream>>>(Whh, WihB, x, XP, bih, bhh, h0, c0,
                                                  mbox, xcnt, out);
  } else {
    lstm_fused<0><<<dim3(NWGF), 256, 0, stream>>>(Whh, WihB, x, XP, bih, bhh, h0, c0,
                                                  mbox, xcnt, out);
  }
}

// Round 13
// 1471.461 us; speedup vs baseline: 1.0263x; 1.0263x over previous
//
#include <hip/hip_runtime.h>

typedef __attribute__((ext_vector_type(8))) short bfrag;   // 8 bf16 (4 VGPRs)
typedef __attribute__((ext_vector_type(4))) float f32x4;   // MFMA C/D
typedef __attribute__((ext_vector_type(4))) int i32x4;     // 16B moves

#define NT 512      // seq len
#define NB 64       // batch
#define KD 512      // D == H == 512
#define NG 2048     // 4*H gate rows
#define GB 4        // batch blocks (16 batch each)
#define GH 16       // h-slices (32 dims each)

#define YS_SZ (NT * NB * KD)          // 16777216
#define HT_OFF YS_SZ
#define CT_OFF (YS_SZ + NB * KD)

// mailbox: [2 parity][GB blocks][256 pairs][16 batch] of u64 {tag32 | bf16x2}
#define MB_BLK_WORDS 4096
#define MB_PAR_WORDS (GB * MB_BLK_WORDS)
#define MB_BYTES (2 * MB_PAR_WORDS * 8)   // 262144

__device__ __forceinline__ unsigned short f2bf(float f) {
  unsigned u = __float_as_uint(f);
  u += 0x7fffu + ((u >> 16) & 1u);
  return (unsigned short)(u >> 16);
}
__device__ __forceinline__ float bf2f(unsigned short h) {
  return __uint_as_float(((unsigned)h) << 16);
}
__device__ __forceinline__ float sigm(float v) { return 1.f / (1.f + __expf(-v)); }
__device__ __forceinline__ float tanh_f(float v) { return 1.f - 2.f / (__expf(2.f * v) + 1.f); }

// ---------------- fp32 -> bf16 convert (vectorized) ----------------
__global__ __launch_bounds__(256) void cvt_bf16(const float* __restrict__ src,
                                                unsigned short* __restrict__ dst, int n8) {
  int i = blockIdx.x * 256 + threadIdx.x;
  if (i >= n8) return;
  const float4 a = *(const float4*)(src + (size_t)i * 8);
  const float4 b = *(const float4*)(src + (size_t)i * 8 + 4);
  i32x4 v;
  v.x = (int)(f2bf(a.x) | ((unsigned)f2bf(a.y) << 16));
  v.y = (int)(f2bf(a.z) | ((unsigned)f2bf(a.w) << 16));
  v.z = (int)(f2bf(b.x) | ((unsigned)f2bf(b.y) << 16));
  v.w = (int)(f2bf(b.z) | ((unsigned)f2bf(b.w) << 16));
  *(i32x4*)(dst + (size_t)i * 8) = v;
}

// ---------------- Phase A: x_proj[t][n][b] = sum_k W_ih[n][k]*x[t][b][k] + b_ih[n] --------
template <int XP32>
__global__ __launch_bounds__(256) void xproj_gemm(const unsigned short* __restrict__ Wb,
                                                  const unsigned short* __restrict__ Xb,
                                                  const float* __restrict__ bias,
                                                  void* __restrict__ XPv) {
  __shared__ unsigned short Wt[64 * 40];
  __shared__ unsigned short Xt[64 * 40];
  const int tid = threadIdx.x;
  const int lane = tid & 63, wid = tid >> 6;
  const int g = lane >> 4, cc = lane & 15;
  const int n0 = blockIdx.x * 64;
  const int t = blockIdx.y;
  const size_t m0 = (size_t)t * 64;
  const int srow = tid >> 2, schunk = (tid & 3) * 8;

  f32x4 acc[4] = {};
  for (int kb = 0; kb < KD; kb += 32) {
    __syncthreads();
    *(i32x4*)&Wt[srow * 40 + schunk] = *(const i32x4*)(Wb + (size_t)(n0 + srow) * KD + kb + schunk);
    *(i32x4*)&Xt[srow * 40 + schunk] = *(const i32x4*)(Xb + (m0 + srow) * KD + kb + schunk);
    __syncthreads();
    bfrag af = *(const bfrag*)&Wt[(wid * 16 + cc) * 40 + g * 8];
#pragma unroll
    for (int mt = 0; mt < 4; ++mt) {
      bfrag bf = *(const bfrag*)&Xt[(mt * 16 + cc) * 40 + g * 8];
      acc[mt] = __builtin_amdgcn_mfma_f32_16x16x32_bf16(af, bf, acc[mt], 0, 0, 0);
    }
  }
  const int nl = wid * 16 + g * 4;
  float bi[4];
#pragma unroll
  for (int r = 0; r < 4; ++r) bi[r] = bias[n0 + nl + r];
#pragma unroll
  for (int mt = 0; mt < 4; ++mt) {
#pragma unroll
    for (int r = 0; r < 4; ++r) {
      float v = acc[mt][r] + bi[r];
      size_t idx = ((size_t)t * NG + n0 + nl + r) * 64 + mt * 16 + cc;
      if (XP32) ((float*)XPv)[idx] = v;
      else ((unsigned short*)XPv)[idx] = f2bf(v);
    }
  }
}

// ---------------- Phase B: persistent recurrence, tagged-data mailbox (fixed poll) --------
// grid = 64: blk = bid>>4 (16 batches), slice = bid&15 (32 dims).
// R6/R11 structure verbatim + ONE change: a phase-alignment backoff (s_sleep ~768 cy,
// hidden under the xp loads' flight) before poll round 1, so the round-1 reads arrive
// at the MALL after the peers' publish stores instead of racing them (which made
// round 1 habitually stale and cost a full extra round per step).
template <int XP32>
__global__ __launch_bounds__(256, 1) void lstm_rec(const unsigned short* __restrict__ Whh,
                                                   const void* __restrict__ XPv,
                                                   const float* __restrict__ bhh,
                                                   const float* __restrict__ h0,
                                                   const float* __restrict__ c0,
                                                   unsigned long long* __restrict__ mbox,
                                                   float* __restrict__ out) {
  __shared__ unsigned short hl[16 * 512];  // h block, XOR-swizzled rows (16KB)
  __shared__ float hf[16 * 33];            // h_new transpose tile (padded)

  const int tid = threadIdx.x;
  const int lane = tid & 63, wid = tid >> 6;
  const int g = lane >> 4, cc = lane & 15;
  const int blk = blockIdx.x >> 4, slice = blockIdx.x & 15;
  const int b0 = blk * 16, d0 = slice * 32;

  // ---- publish our slice of h0 (tag=1) into parity-0 mailbox, ASAP (1 word/thread)
  {
    const int lp = tid >> 4, b = tid & 15;  // local pair, batch row
    const int d = d0 + lp * 2;
    const float* hp = h0 + (size_t)(b0 + b) * KD + d;
    unsigned d32 = (unsigned)f2bf(hp[0]) | ((unsigned)f2bf(hp[1]) << 16);
    __hip_atomic_store(mbox + (size_t)blk * MB_BLK_WORDS + ((d0 >> 1) + lp) * 16 + b,
                       (1ull << 32) | (unsigned long long)d32, __ATOMIC_RELAXED,
                       __HIP_MEMORY_SCOPE_AGENT);
  }

  // ---- preload W_hh slice into registers: 2 tiles x 16 k-steps of bf16x8
  bfrag w[2][16];
#pragma unroll
  for (int j = 0; j < 2; ++j) {
    const int tt = wid * 2 + j;
    const int r = tt * 16 + cc;  // A-operand row = lane&15
    const size_t n = (size_t)(r & 3) * KD + d0 + (r >> 2);
#pragma unroll
    for (int ks = 0; ks < 16; ++ks)
      w[j][ks] = *(const bfrag*)(Whh + n * KD + ks * 32 + g * 8);
  }
  float bh[2][4], creg[2];
#pragma unroll
  for (int j = 0; j < 2; ++j) {
    const int d = d0 + (wid * 2 + j) * 4 + g;
#pragma unroll
    for (int r = 0; r < 4; ++r) bh[j][r] = bhh[r * KD + d];
    creg[j] = c0[(b0 + cc) * KD + d];
  }

  for (int t = 0; t < NT; ++t) {
    // prefetch x_proj (independent of h; drains under the first poll round)
    float xp[2][4];
#pragma unroll
    for (int j = 0; j < 2; ++j) {
      const int d = d0 + (wid * 2 + j) * 4 + g;
#pragma unroll
      for (int r = 0; r < 4; ++r) {
        size_t idx = ((size_t)t * NG + r * KD + d) * 64 + b0 + cc;
        xp[j][r] = XP32 ? ((const float*)XPv)[idx] : bf2f(((const unsigned short*)XPv)[idx]);
      }
    }
    // ---- phase-alignment backoff: let peers' publish stores land at the MALL
    // before round-1 reads arrive (sleep hides under the xp loads in flight)
    __builtin_amdgcn_s_sleep(12);
    // ---- single-hop receive: batched asm poll of 16 tagged words per thread
    const unsigned long long* mbr =
        mbox + (size_t)(t & 1) * MB_PAR_WORDS + (size_t)blk * MB_BLK_WORDS;
    const unsigned tg = (unsigned)(t + 1);
    unsigned long long q0, q1, q2, q3, q4, q5, q6, q7, q8, q9, q10, q11, q12, q13, q14, q15;
#define PISSUE(r)                                                        \
  asm volatile("global_load_dwordx2 %0, %1, %2 sc1"                      \
               : "=v"(q##r)                                              \
               : "v"((unsigned)(tid * 8 + r * 2048)), "s"(mbr));
    for (;;) {
      PISSUE(0) PISSUE(1) PISSUE(2) PISSUE(3) PISSUE(4) PISSUE(5) PISSUE(6) PISSUE(7)
      PISSUE(8) PISSUE(9) PISSUE(10) PISSUE(11) PISSUE(12) PISSUE(13) PISSUE(14) PISSUE(15)
      asm volatile("s_waitcnt vmcnt(0)" ::: "memory");
      __builtin_amdgcn_sched_barrier(0);
      unsigned ok = 1u;
#define PCHK(r) ok &= ((unsigned)(q##r >> 32) == tg) ? 1u : 0u;
      PCHK(0) PCHK(1) PCHK(2) PCHK(3) PCHK(4) PCHK(5) PCHK(6) PCHK(7)
      PCHK(8) PCHK(9) PCHK(10) PCHK(11) PCHK(12) PCHK(13) PCHK(14) PCHK(15)
      if (__all(ok)) break;
    }
#undef PISSUE
#undef PCHK
    // unpack into swizzled LDS: word (r*256+tid) = pair p = r*16 + (tid>>4), batch b = tid&15
    {
      const int b = tid & 15, pq = tid >> 4;
      const int bb = b * 1024, bx = (b & 7) << 4;
#define PUNP(r) \
  *(unsigned*)((char*)hl + bb + (((r * 16 + pq) * 4) ^ bx)) = (unsigned)q##r;
      PUNP(0) PUNP(1) PUNP(2) PUNP(3) PUNP(4) PUNP(5) PUNP(6) PUNP(7)
      PUNP(8) PUNP(9) PUNP(10) PUNP(11) PUNP(12) PUNP(13) PUNP(14) PUNP(15)
#undef PUNP
    }
    __syncthreads();
    // gates = W_slice @ h^T  (4 accumulators: chains of 8)
    f32x4 p00 = {0.f, 0.f, 0.f, 0.f}, p01 = {0.f, 0.f, 0.f, 0.f};
    f32x4 p10 = {0.f, 0.f, 0.f, 0.f}, p11 = {0.f, 0.f, 0.f, 0.f};
#pragma unroll
    for (int ks = 0; ks < 8; ++ks) {
      const int off = ks * 64 + g * 16;
      bfrag hb = *(const bfrag*)((const char*)hl + cc * 1024 + (off ^ ((cc & 7) << 4)));
      p00 = __builtin_amdgcn_mfma_f32_16x16x32_bf16(w[0][ks], hb, p00, 0, 0, 0);
      p10 = __builtin_amdgcn_mfma_f32_16x16x32_bf16(w[1][ks], hb, p10, 0, 0, 0);
    }
#pragma unroll
    for (int ks = 8; ks < 16; ++ks) {
      const int off = ks * 64 + g * 16;
      bfrag hb = *(const bfrag*)((const char*)hl + cc * 1024 + (off ^ ((cc & 7) << 4)));
      p01 = __builtin_amdgcn_mfma_f32_16x16x32_bf16(w[0][ks], hb, p01, 0, 0, 0);
      p11 = __builtin_amdgcn_mfma_f32_16x16x32_bf16(w[1][ks], hb, p11, 0, 0, 0);
    }
    const f32x4 acc0 = p00 + p01, acc1 = p10 + p11;
    // pointwise (i,f,g,o thread-local)
    float hnv[2];
#pragma unroll
    for (int j = 0; j < 2; ++j) {
      const f32x4 a = j ? acc1 : acc0;
      float gi = a[0] + xp[j][0] + bh[j][0];
      float gf = a[1] + xp[j][1] + bh[j][1];
      float gg = a[2] + xp[j][2] + bh[j][2];
      float go = a[3] + xp[j][3] + bh[j][3];
      float cn = sigm(gf) * creg[j] + sigm(gi) * tanh_f(gg);
      creg[j] = cn;
      hnv[j] = sigm(go) * tanh_f(cn);
      if (t == NT - 1) out[CT_OFF + (size_t)(b0 + cc) * KD + d0 + (wid * 8 + j * 4 + g)] = cn;
    }
    // ---- single-hop publish: pair dims via shfl, store (tag|bf16x2) words NOW; no drain
    {
      unsigned long long* mbw =
          mbox + (size_t)((t + 1) & 1) * MB_PAR_WORDS + (size_t)blk * MB_BLK_WORDS;
      const unsigned long long tagn = (unsigned long long)(unsigned)(t + 2) << 32;
      const float o0 = __shfl_xor(hnv[0], 16);
      const float o1 = __shfl_xor(hnv[1], 16);
      if (!(g & 1)) {
        const unsigned w0 = (unsigned)f2bf(hnv[0]) | ((unsigned)f2bf(o0) << 16);
        const unsigned w1 = (unsigned)f2bf(hnv[1]) | ((unsigned)f2bf(o1) << 16);
        const int p0 = (d0 >> 1) + wid * 4 + (g >> 1);
        const int p1 = p0 + 2;
        __hip_atomic_store(mbw + p0 * 16 + cc, tagn | (unsigned long long)w0,
                           __ATOMIC_RELAXED, __HIP_MEMORY_SCOPE_AGENT);
        __hip_atomic_store(mbw + p1 * 16 + cc, tagn | (unsigned long long)w1,
                           __ATOMIC_RELAXED, __HIP_MEMORY_SCOPE_AGENT);
      }
    }
    // transpose h_new for coalesced fp32 output stores (off critical path)
#pragma unroll
    for (int j = 0; j < 2; ++j) hf[cc * 33 + (wid * 8 + j * 4 + g)] = hnv[j];
    __syncthreads();
    if (tid < 128) {
      const int b = tid >> 3, dg = (tid & 7) * 4;
      float4 hv;
      hv.x = hf[b * 33 + dg];
      hv.y = hf[b * 33 + dg + 1];
      hv.z = hf[b * 33 + dg + 2];
      hv.w = hf[b * 33 + dg + 3];
      *(float4*)(out + (size_t)t * NB * KD + (size_t)(b0 + b) * KD + d0 + dg) = hv;
      if (t == NT - 1)
        *(float4*)(out + HT_OFF + (size_t)(b0 + b) * KD + d0 + dg) = hv;
    }
  }
}

extern "C" void kernel_launch(void* const* d_in, const int* in_sizes, int n_in,
                              void* d_out, int out_size, void* d_ws, size_t ws_size,
                              hipStream_t stream) {
  const float* x = (const float*)d_in[0];
  const float* h0 = (const float*)d_in[1];
  const float* c0 = (const float*)d_in[2];
  const float* Wih = (const float*)d_in[3];
  const float* Whh = (const float*)d_in[4];
  const float* bih = (const float*)d_in[5];
  const float* bhh = (const float*)d_in[6];
  float* out = (float*)d_out;
  char* ws = (char*)d_ws;

  unsigned long long* mbox = (unsigned long long*)ws;                      // 256KB
  unsigned short* WhhB = (unsigned short*)(ws + MB_BYTES);                 // 2MB
  unsigned short* WihB = (unsigned short*)(ws + MB_BYTES + 2097152);       // 2MB
  unsigned short* XB = (unsigned short*)(ws + MB_BYTES + 2 * 2097152);     // 32MB
  const size_t xp_off = MB_BYTES + 2ull * 2097152 + 33554432;
  void* XP = (void*)(ws + xp_off);
  const bool xp32 = ws_size >= xp_off + (size_t)NT * NG * 64 * 4;

  hipMemsetAsync(ws, 0, MB_BYTES, stream);  // reset mailbox tags (poison/replay safe)

  const int nx8 = NT * NB * KD / 8;
  const int nw8 = NG * KD / 8;
  cvt_bf16<<<dim3(nx8 / 256), 256, 0, stream>>>(x, XB, nx8);
  cvt_bf16<<<dim3(nw8 / 256), 256, 0, stream>>>(Wih, WihB, nw8);
  cvt_bf16<<<dim3(nw8 / 256), 256, 0, stream>>>(Whh, WhhB, nw8);

  if (xp32) {
    xproj_gemm<1><<<dim3(NG / 64, NT), 256, 0, stream>>>(WihB, XB, bih, XP);
    lstm_rec<1><<<dim3(GB * GH), 256, 0, stream>>>(WhhB, XP, bhh, h0, c0, mbox, out);
  } else {
    xproj_gemm<0><<<dim3(NG / 64, NT), 256, 0, stream>>>(WihB, XB, bih, XP);
    lstm_rec<0><<<dim3(GB * GH), 256, 0, stream>>>(WhhB, XP, bhh, h0, c0, mbox, out);
  }
}

// Round 14
// 1461.297 us; speedup vs baseline: 1.0334x; 1.0070x over previous
//
#include <hip/hip_runtime.h>

typedef __attribute__((ext_vector_type(8))) short bfrag;   // 8 bf16 (4 VGPRs)
typedef __attribute__((ext_vector_type(4))) float f32x4;   // MFMA C/D
typedef __attribute__((ext_vector_type(4))) int i32x4;     // 16B moves

#define NT 512      // seq len
#define NB 64       // batch
#define KD 512      // D == H == 512
#define NG 2048     // 4*H gate rows
#define GB 4        // batch blocks (16 batch each)
#define GH 16       // h-slices (32 dims each)

#define YS_SZ (NT * NB * KD)          // 16777216
#define HT_OFF YS_SZ
#define CT_OFF (YS_SZ + NB * KD)

// mailbox: [2 parity][GB blocks][256 pairs][16 batch] of u64 {tag32 | bf16x2}
#define MB_BLK_WORDS 4096
#define MB_PAR_WORDS (GB * MB_BLK_WORDS)
#define MB_BYTES (2 * MB_PAR_WORDS * 8)   // 262144

__device__ __forceinline__ unsigned short f2bf(float f) {
  unsigned u = __float_as_uint(f);
  u += 0x7fffu + ((u >> 16) & 1u);
  return (unsigned short)(u >> 16);
}
__device__ __forceinline__ float bf2f(unsigned short h) {
  return __uint_as_float(((unsigned)h) << 16);
}
__device__ __forceinline__ float sigm(float v) { return 1.f / (1.f + __expf(-v)); }
__device__ __forceinline__ float tanh_f(float v) { return 1.f - 2.f / (__expf(2.f * v) + 1.f); }

// ---------------- fp32 -> bf16 convert (vectorized) ----------------
__global__ __launch_bounds__(256) void cvt_bf16(const float* __restrict__ src,
                                                unsigned short* __restrict__ dst, int n8) {
  int i = blockIdx.x * 256 + threadIdx.x;
  if (i >= n8) return;
  const float4 a = *(const float4*)(src + (size_t)i * 8);
  const float4 b = *(const float4*)(src + (size_t)i * 8 + 4);
  i32x4 v;
  v.x = (int)(f2bf(a.x) | ((unsigned)f2bf(a.y) << 16));
  v.y = (int)(f2bf(a.z) | ((unsigned)f2bf(a.w) << 16));
  v.z = (int)(f2bf(b.x) | ((unsigned)f2bf(b.y) << 16));
  v.w = (int)(f2bf(b.z) | ((unsigned)f2bf(b.w) << 16));
  *(i32x4*)(dst + (size_t)i * 8) = v;
}

// ---------------- Phase A: x_proj[t][n][b] = sum_k W_ih[n][k]*x[t][b][k] + b_ih[n] --------
template <int XP32>
__global__ __launch_bounds__(256) void xproj_gemm(const unsigned short* __restrict__ Wb,
                                                  const unsigned short* __restrict__ Xb,
                                                  const float* __restrict__ bias,
                                                  void* __restrict__ XPv) {
  __shared__ unsigned short Wt[64 * 40];
  __shared__ unsigned short Xt[64 * 40];
  const int tid = threadIdx.x;
  const int lane = tid & 63, wid = tid >> 6;
  const int g = lane >> 4, cc = lane & 15;
  const int n0 = blockIdx.x * 64;
  const int t = blockIdx.y;
  const size_t m0 = (size_t)t * 64;
  const int srow = tid >> 2, schunk = (tid & 3) * 8;

  f32x4 acc[4] = {};
  for (int kb = 0; kb < KD; kb += 32) {
    __syncthreads();
    *(i32x4*)&Wt[srow * 40 + schunk] = *(const i32x4*)(Wb + (size_t)(n0 + srow) * KD + kb + schunk);
    *(i32x4*)&Xt[srow * 40 + schunk] = *(const i32x4*)(Xb + (m0 + srow) * KD + kb + schunk);
    __syncthreads();
    bfrag af = *(const bfrag*)&Wt[(wid * 16 + cc) * 40 + g * 8];
#pragma unroll
    for (int mt = 0; mt < 4; ++mt) {
      bfrag bf = *(const bfrag*)&Xt[(mt * 16 + cc) * 40 + g * 8];
      acc[mt] = __builtin_amdgcn_mfma_f32_16x16x32_bf16(af, bf, acc[mt], 0, 0, 0);
    }
  }
  const int nl = wid * 16 + g * 4;
  float bi[4];
#pragma unroll
  for (int r = 0; r < 4; ++r) bi[r] = bias[n0 + nl + r];
#pragma unroll
  for (int mt = 0; mt < 4; ++mt) {
#pragma unroll
    for (int r = 0; r < 4; ++r) {
      float v = acc[mt][r] + bi[r];
      size_t idx = ((size_t)t * NG + n0 + nl + r) * 64 + mt * 16 + cc;
      if (XP32) ((float*)XPv)[idx] = v;
      else ((unsigned short*)XPv)[idx] = f2bf(v);
    }
  }
}

// ---------------- Phase B: persistent recurrence, tagged-data mailbox (fixed poll) --------
// grid = 64: blk = bid>>4 (16 batches), slice = bid&15 (32 dims).
// Single-hop exchange: producers store (tag32|bf16x2) u64 words (relaxed agent = sc1,
// 64-bit single-copy atomic) straight from the pointwise registers — NO drains, NO
// flags, NO extra barriers. Consumers poll the data words themselves with ONE inline-asm
// batch of 16 global_load_dwordx2 sc1 + a single vmcnt(0) per round; uniform re-issue of
// all 16 on any miss (no divergence). Exact-tag accept: within a parity buffer the tag
// for step t+1 can only advance to t+3 after every WG consumed t+1 (transitive dep).
template <int XP32>
__global__ __launch_bounds__(256, 1) void lstm_rec(const unsigned short* __restrict__ Whh,
                                                   const void* __restrict__ XPv,
                                                   const float* __restrict__ bhh,
                                                   const float* __restrict__ h0,
                                                   const float* __restrict__ c0,
                                                   unsigned long long* __restrict__ mbox,
                                                   float* __restrict__ out) {
  __shared__ unsigned short hl[16 * 512];  // h block, XOR-swizzled rows (16KB)
  __shared__ float hf[16 * 33];            // h_new transpose tile (padded)

  const int tid = threadIdx.x;
  const int lane = tid & 63, wid = tid >> 6;
  const int g = lane >> 4, cc = lane & 15;
  const int blk = blockIdx.x >> 4, slice = blockIdx.x & 15;
  const int b0 = blk * 16, d0 = slice * 32;

  // ---- publish our slice of h0 (tag=1) into parity-0 mailbox, ASAP (1 word/thread)
  {
    const int lp = tid >> 4, b = tid & 15;  // local pair, batch row
    const int d = d0 + lp * 2;
    const float* hp = h0 + (size_t)(b0 + b) * KD + d;
    unsigned d32 = (unsigned)f2bf(hp[0]) | ((unsigned)f2bf(hp[1]) << 16);
    __hip_atomic_store(mbox + (size_t)blk * MB_BLK_WORDS + ((d0 >> 1) + lp) * 16 + b,
                       (1ull << 32) | (unsigned long long)d32, __ATOMIC_RELAXED,
                       __HIP_MEMORY_SCOPE_AGENT);
  }

  // ---- preload W_hh slice into registers: 2 tiles x 16 k-steps of bf16x8
  bfrag w[2][16];
#pragma unroll
  for (int j = 0; j < 2; ++j) {
    const int tt = wid * 2 + j;
    const int r = tt * 16 + cc;  // A-operand row = lane&15
    const size_t n = (size_t)(r & 3) * KD + d0 + (r >> 2);
#pragma unroll
    for (int ks = 0; ks < 16; ++ks)
      w[j][ks] = *(const bfrag*)(Whh + n * KD + ks * 32 + g * 8);
  }
  float bh[2][4], creg[2];
#pragma unroll
  for (int j = 0; j < 2; ++j) {
    const int d = d0 + (wid * 2 + j) * 4 + g;
#pragma unroll
    for (int r = 0; r < 4; ++r) bh[j][r] = bhh[r * KD + d];
    creg[j] = c0[(b0 + cc) * KD + d];
  }

  for (int t = 0; t < NT; ++t) {
    // prefetch x_proj (independent of h; drains under the first poll round)
    float xp[2][4];
#pragma unroll
    for (int j = 0; j < 2; ++j) {
      const int d = d0 + (wid * 2 + j) * 4 + g;
#pragma unroll
      for (int r = 0; r < 4; ++r) {
        size_t idx = ((size_t)t * NG + r * KD + d) * 64 + b0 + cc;
        xp[j][r] = XP32 ? ((const float*)XPv)[idx] : bf2f(((const unsigned short*)XPv)[idx]);
      }
    }
    // ---- single-hop receive: batched asm poll of 16 tagged words per thread
    const unsigned long long* mbr =
        mbox + (size_t)(t & 1) * MB_PAR_WORDS + (size_t)blk * MB_BLK_WORDS;
    const unsigned tg = (unsigned)(t + 1);
    unsigned long long q0, q1, q2, q3, q4, q5, q6, q7, q8, q9, q10, q11, q12, q13, q14, q15;
#define PISSUE(r)                                                        \
  asm volatile("global_load_dwordx2 %0, %1, %2 sc1"                      \
               : "=v"(q##r)                                              \
               : "v"((unsigned)(tid * 8 + r * 2048)), "s"(mbr));
    for (;;) {
      PISSUE(0) PISSUE(1) PISSUE(2) PISSUE(3) PISSUE(4) PISSUE(5) PISSUE(6) PISSUE(7)
      PISSUE(8) PISSUE(9) PISSUE(10) PISSUE(11) PISSUE(12) PISSUE(13) PISSUE(14) PISSUE(15)
      asm volatile("s_waitcnt vmcnt(0)" ::: "memory");
      __builtin_amdgcn_sched_barrier(0);
      unsigned ok = 1u;
#define PCHK(r) ok &= ((unsigned)(q##r >> 32) == tg) ? 1u : 0u;
      PCHK(0) PCHK(1) PCHK(2) PCHK(3) PCHK(4) PCHK(5) PCHK(6) PCHK(7)
      PCHK(8) PCHK(9) PCHK(10) PCHK(11) PCHK(12) PCHK(13) PCHK(14) PCHK(15)
      if (__all(ok)) break;
    }
#undef PISSUE
#undef PCHK
    // unpack into swizzled LDS: word (r*256+tid) = pair p = r*16 + (tid>>4), batch b = tid&15
    {
      const int b = tid & 15, pq = tid >> 4;
      const int bb = b * 1024, bx = (b & 7) << 4;
#define PUNP(r) \
  *(unsigned*)((char*)hl + bb + (((r * 16 + pq) * 4) ^ bx)) = (unsigned)q##r;
      PUNP(0) PUNP(1) PUNP(2) PUNP(3) PUNP(4) PUNP(5) PUNP(6) PUNP(7)
      PUNP(8) PUNP(9) PUNP(10) PUNP(11) PUNP(12) PUNP(13) PUNP(14) PUNP(15)
#undef PUNP
    }
    __syncthreads();
    // gates = W_slice @ h^T  (4 accumulators: chains of 8)
    f32x4 p00 = {0.f, 0.f, 0.f, 0.f}, p01 = {0.f, 0.f, 0.f, 0.f};
    f32x4 p10 = {0.f, 0.f, 0.f, 0.f}, p11 = {0.f, 0.f, 0.f, 0.f};
#pragma unroll
    for (int ks = 0; ks < 8; ++ks) {
      const int off = ks * 64 + g * 16;
      bfrag hb = *(const bfrag*)((const char*)hl + cc * 1024 + (off ^ ((cc & 7) << 4)));
      p00 = __builtin_amdgcn_mfma_f32_16x16x32_bf16(w[0][ks], hb, p00, 0, 0, 0);
      p10 = __builtin_amdgcn_mfma_f32_16x16x32_bf16(w[1][ks], hb, p10, 0, 0, 0);
    }
#pragma unroll
    for (int ks = 8; ks < 16; ++ks) {
      const int off = ks * 64 + g * 16;
      bfrag hb = *(const bfrag*)((const char*)hl + cc * 1024 + (off ^ ((cc & 7) << 4)));
      p01 = __builtin_amdgcn_mfma_f32_16x16x32_bf16(w[0][ks], hb, p01, 0, 0, 0);
      p11 = __builtin_amdgcn_mfma_f32_16x16x32_bf16(w[1][ks], hb, p11, 0, 0, 0);
    }
    const f32x4 acc0 = p00 + p01, acc1 = p10 + p11;
    // pointwise (i,f,g,o thread-local)
    float hnv[2];
#pragma unroll
    for (int j = 0; j < 2; ++j) {
      const f32x4 a = j ? acc1 : acc0;
      float gi = a[0] + xp[j][0] + bh[j][0];
      float gf = a[1] + xp[j][1] + bh[j][1];
      float gg = a[2] + xp[j][2] + bh[j][2];
      float go = a[3] + xp[j][3] + bh[j][3];
      float cn = sigm(gf) * creg[j] + sigm(gi) * tanh_f(gg);
      creg[j] = cn;
      hnv[j] = sigm(go) * tanh_f(cn);
      if (t == NT - 1) out[CT_OFF + (size_t)(b0 + cc) * KD + d0 + (wid * 8 + j * 4 + g)] = cn;
    }
    // ---- single-hop publish: pair dims via shfl, store (tag|bf16x2) words NOW; no drain
    {
      unsigned long long* mbw =
          mbox + (size_t)((t + 1) & 1) * MB_PAR_WORDS + (size_t)blk * MB_BLK_WORDS;
      const unsigned long long tagn = (unsigned long long)(unsigned)(t + 2) << 32;
      const float o0 = __shfl_xor(hnv[0], 16);
      const float o1 = __shfl_xor(hnv[1], 16);
      if (!(g & 1)) {
        const unsigned w0 = (unsigned)f2bf(hnv[0]) | ((unsigned)f2bf(o0) << 16);
        const unsigned w1 = (unsigned)f2bf(hnv[1]) | ((unsigned)f2bf(o1) << 16);
        const int p0 = (d0 >> 1) + wid * 4 + (g >> 1);
        const int p1 = p0 + 2;
        __hip_atomic_store(mbw + p0 * 16 + cc, tagn | (unsigned long long)w0,
                           __ATOMIC_RELAXED, __HIP_MEMORY_SCOPE_AGENT);
        __hip_atomic_store(mbw + p1 * 16 + cc, tagn | (unsigned long long)w1,
                           __ATOMIC_RELAXED, __HIP_MEMORY_SCOPE_AGENT);
      }
    }
    // transpose h_new for coalesced fp32 output stores (off critical path)
#pragma unroll
    for (int j = 0; j < 2; ++j) hf[cc * 33 + (wid * 8 + j * 4 + g)] = hnv[j];
    __syncthreads();
    if (tid < 128) {
      const int b = tid >> 3, dg = (tid & 7) * 4;
      float4 hv;
      hv.x = hf[b * 33 + dg];
      hv.y = hf[b * 33 + dg + 1];
      hv.z = hf[b * 33 + dg + 2];
      hv.w = hf[b * 33 + dg + 3];
      *(float4*)(out + (size_t)t * NB * KD + (size_t)(b0 + b) * KD + d0 + dg) = hv;
      if (t == NT - 1)
        *(float4*)(out + HT_OFF + (size_t)(b0 + b) * KD + d0 + dg) = hv;
    }
  }
}

extern "C" void kernel_launch(void* const* d_in, const int* in_sizes, int n_in,
                              void* d_out, int out_size, void* d_ws, size_t ws_size,
                              hipStream_t stream) {
  const float* x = (const float*)d_in[0];
  const float* h0 = (const float*)d_in[1];
  const float* c0 = (const float*)d_in[2];
  const float* Wih = (const float*)d_in[3];
  const float* Whh = (const float*)d_in[4];
  const float* bih = (const float*)d_in[5];
  const float* bhh = (const float*)d_in[6];
  float* out = (float*)d_out;
  char* ws = (char*)d_ws;

  unsigned long long* mbox = (unsigned long long*)ws;                      // 256KB
  unsigned short* WhhB = (unsigned short*)(ws + MB_BYTES);                 // 2MB
  unsigned short* WihB = (unsigned short*)(ws + MB_BYTES + 2097152);       // 2MB
  unsigned short* XB = (unsigned short*)(ws + MB_BYTES + 2 * 2097152);     // 32MB
  const size_t xp_off = MB_BYTES + 2ull * 2097152 + 33554432;
  void* XP = (void*)(ws + xp_off);
  const bool xp32 = ws_size >= xp_off + (size_t)NT * NG * 64 * 4;

  hipMemsetAsync(ws, 0, MB_BYTES, stream);  // reset mailbox tags (poison/replay safe)

  const int nx8 = NT * NB * KD / 8;
  const int nw8 = NG * KD / 8;
  cvt_bf16<<<dim3(nx8 / 256), 256, 0, stream>>>(x, XB, nx8);
  cvt_bf16<<<dim3(nw8 / 256), 256, 0, stream>>>(Wih, WihB, nw8);
  cvt_bf16<<<dim3(nw8 / 256), 256, 0, stream>>>(Whh, WhhB, nw8);

  if (xp32) {
    xproj_gemm<1><<<dim3(NG / 64, NT), 256, 0, stream>>>(WihB, XB, bih, XP);
    lstm_rec<1><<<dim3(GB * GH), 256, 0, stream>>>(WhhB, XP, bhh, h0, c0, mbox, out);
  } else {
    xproj_gemm<0><<<dim3(NG / 64, NT), 256, 0, stream>>>(WihB, XB, bih, XP);
    lstm_rec<0><<<dim3(GB * GH), 256, 0, stream>>>(WhhB, XP, bhh, h0, c0, mbox, out);
  }
}